// Round 4
// baseline (98.568 us; speedup 1.0000x reference)
//
#include <hip/hip_runtime.h>
#include <hip/hip_bf16.h>

typedef __attribute__((ext_vector_type(8))) short bf16x8;
typedef __attribute__((ext_vector_type(4))) float f32x4;

#define CIN   128
#define COUT  256
#define NIMG  32
#define HWDIM 56
#define HPAD  58
#define KTOT  1152            // 9*128
#define HWIMG 3136
#define MTOT  100352
#define BN    256             // spatial tile; all 256 couts per block
#define BK    64
#define NT    18              // K tiles of 64
#define BSZA  (COUT * BK)     // 16384 shorts per region

__device__ __forceinline__ void gload16(const void* g, void* l) {
  __builtin_amdgcn_global_load_lds((const __attribute__((address_space(1))) void*)g,
                                   (__attribute__((address_space(3))) void*)l,
                                   16, 0, 0);
}

// ---------------- fused pre-pass: halo zero + x->NHWC bf16 + sign(w) ------
__global__ __launch_bounds__(256)
void prep_all(const float* __restrict__ x, const float* __restrict__ w,
              __hip_bfloat16* __restrict__ xp, __hip_bfloat16* __restrict__ wt) {
  __shared__ float tile[CIN * 57];
  const int bid = blockIdx.x;
  const int t = threadIdx.x;
  if (bid < NIMG * HPAD) {
    const int n = bid / HPAD;
    const int h = bid - n * HPAD;
    __hip_bfloat16* dstrow = xp + ((size_t)n * HPAD + h) * HPAD * CIN;
    int4 z; z.x = 0; z.y = 0; z.z = 0; z.w = 0;
    if (h == 0 || h == HPAD - 1) {
      for (int i = t; i < (HPAD * CIN) / 8; i += 256)
        reinterpret_cast<int4*>(dstrow)[i] = z;
      return;
    }
    const float* src = x + (size_t)n * CIN * HWIMG + (size_t)(h - 1) * HWDIM;
    for (int i = t; i < CIN * HWDIM; i += 256) {
      int c = i / HWDIM;
      int wd = i - c * HWDIM;
      tile[c * 57 + wd] = src[(size_t)c * HWIMG + wd];
    }
    if (t < 32) {
      int side = t >> 4;
      reinterpret_cast<int4*>(dstrow + (side ? (HPAD - 1) : 0) * CIN)[t & 15] = z;
    }
    __syncthreads();
    __hip_bfloat16* dst = dstrow + CIN;
    for (int o = t; o < HWDIM * 64; o += 256) {
      int wd = o >> 6;
      int c = (o & 63) * 2;
      __hip_bfloat162 pr;
      pr.x = __float2bfloat16(tile[c * 57 + wd]);
      pr.y = __float2bfloat16(tile[(c + 1) * 57 + wd]);
      *reinterpret_cast<__hip_bfloat162*>(dst + (size_t)wd * CIN + c) = pr;
    }
  } else {
    int o = (bid - NIMG * HPAD) * 256 + t;
    int cout = o / KTOT;
    int r = o - cout * KTOT;
    int tap = r >> 7;
    int cin = r & 127;
    float v = w[((size_t)cout * CIN + cin) * 9 + tap];
    wt[o] = __float2bfloat16(v > 0.f ? 1.f : (v < 0.f ? -1.f : 0.f));
  }
}

// ---------------- main: 256x256, BK=64, 4-phase, clean vmcnt ledger -------
__global__ __launch_bounds__(512, 2)
void bconv(const short* __restrict__ xp, const short* __restrict__ wt,
           const float* __restrict__ bias, float* __restrict__ out) {
  __shared__ short lds[2][2 * BSZA];   // per buf: A [256][64] | B [256][64]

  const int tid  = threadIdx.x;
  const int lane = tid & 63;
  const int wv   = tid >> 6;       // 0..7
  const int wm   = wv >> 2;        // 0,1
  const int wn   = wv & 3;         // 0..3
  const int s0   = blockIdx.x * BN;

  // staging: unit = 64 rows; 512 thr x 16B = one unit per gload
  const int srow = tid >> 3;       // 0..63
  const int swz  = (tid & 7) ^ (srow & 7);

  int xb[4];
#pragma unroll
  for (int u = 0; u < 4; ++u) {
    int m  = s0 + u * 64 + srow;
    int n  = m / HWIMG;
    int hw = m - n * HWIMG;
    int hh = hw / HWDIM;
    int ww = hw - hh * HWDIM;
    xb[u] = ((n * HPAD + hh) * HPAD + ww) * CIN + swz * 8;
  }
  const int wb = srow * KTOT + swz * 8;

#define STAGE_A(C, U, KO) \
  gload16(wt + ((U) * 64) * KTOT + wb + (KO), &lds[C][((U) * 64 + wv * 8) * BK])
#define STAGE_B(C, U, XKO) \
  gload16(xp + xb[U] + (XKO), &lds[C][BSZA + ((U) * 64 + wv * 8) * BK])

  const int rlo = lane & 15;
  const int kq  = lane >> 4;
  const int swr = rlo & 7;

  f32x4 acc[8][4] = {};
  bf16x8 bx[4][2], afA[2][2], afB[2][2];

#define AF_LOAD(DST, MI) \
  _Pragma("unroll") for (int kk = 0; kk < 2; ++kk) \
    DST[kk] = *(const bf16x8*)&A[((((MI) >> 1) * 64 + wm * 32 + ((MI) & 1) * 16 + rlo) * BK) + (((kk * 4) + kq) ^ swr) * 8];

  // swapped operands: D rows = spatial (bx), cols = cout (af)
#define CLUSTER(MA, MB, AFR) \
  _Pragma("unroll") for (int kk = 0; kk < 2; ++kk) { \
    _Pragma("unroll") for (int nf = 0; nf < 4; ++nf) \
      acc[MA][nf] = __builtin_amdgcn_mfma_f32_16x16x32_bf16(bx[nf][kk], AFR[0][kk], acc[MA][nf], 0, 0, 0); \
    _Pragma("unroll") for (int nf = 0; nf < 4; ++nf) \
      acc[MB][nf] = __builtin_amdgcn_mfma_f32_16x16x32_bf16(bx[nf][kk], AFR[1][kk], acc[MB][nf], 0, 0, 0); \
  }

#define BAR()  __builtin_amdgcn_s_barrier()
#define SBAR() __builtin_amdgcn_sched_barrier(0)
#define VM(N)  asm volatile("s_waitcnt vmcnt(" #N ")" ::: "memory")

  // prologue: tile 0 (tap 0 -> xko = 0, ko = 0); leave A2,A3 in flight
  STAGE_B(0, 0, 0); STAGE_B(0, 1, 0); STAGE_B(0, 2, 0); STAGE_B(0, 3, 0);
  STAGE_A(0, 0, 0); STAGE_A(0, 1, 0);
  STAGE_A(0, 2, 0); STAGE_A(0, 3, 0);
  VM(2);
  BAR();

  for (int t = 0; t < NT; ++t) {
    const int c  = t & 1;
    const int cn = c ^ 1;
    const short* A = &lds[c][0];
    const short* B = &lds[c][BSZA];
    const bool st = (t + 1 < NT);
    const int t1   = t + 1;
    const int tap1 = t1 >> 1;
    const int kh1  = tap1 / 3;
    const int kw1  = tap1 - kh1 * 3;
    const int xko1 = (kh1 * HPAD + kw1) * CIN + (t1 & 1) * BK;
    const int ko1  = t1 * BK;

    // ---- ph0: read bx full + af mi0..3; stage B0,B1,B2(t+1) ----
#pragma unroll
    for (int nf = 0; nf < 4; ++nf)
#pragma unroll
      for (int kk = 0; kk < 2; ++kk)
        bx[nf][kk] = *(const bf16x8*)&B[(wn * 64 + nf * 16 + rlo) * BK + (((kk * 4) + kq) ^ swr) * 8];
    AF_LOAD(afA[0], 0) AF_LOAD(afA[1], 1) AF_LOAD(afB[0], 2) AF_LOAD(afB[1], 3)
    if (st) { STAGE_B(cn, 0, xko1); STAGE_B(cn, 1, xko1); STAGE_B(cn, 2, xko1); }
    BAR(); SBAR();
    __builtin_amdgcn_s_setprio(1);
    CLUSTER(0, 1, afA)
    __builtin_amdgcn_s_setprio(0);
    BAR();

    // ---- ph1: no reads; stage B3,A0,A1(t+1); vmcnt(6) guards A2,A3(t) ----
    if (st) { STAGE_B(cn, 3, xko1); STAGE_A(cn, 0, ko1); STAGE_A(cn, 1, ko1); }
    BAR(); SBAR();
    __builtin_amdgcn_s_setprio(1);
    CLUSTER(2, 3, afB)
    __builtin_amdgcn_s_setprio(0);
    if (st) VM(6); else VM(0);
    BAR();

    // ---- ph2: read af mi4..7; stage A2(t+1) ----
    AF_LOAD(afA[0], 4) AF_LOAD(afA[1], 5) AF_LOAD(afB[0], 6) AF_LOAD(afB[1], 7)
    if (st) { STAGE_A(cn, 2, ko1); }
    BAR(); SBAR();
    __builtin_amdgcn_s_setprio(1);
    CLUSTER(4, 5, afA)
    __builtin_amdgcn_s_setprio(0);
    BAR();

    // ---- ph3: no reads; stage A3(t+1); vmcnt(2) guards B(t+1)+A0,A1(t+1) ----
    if (st) { STAGE_A(cn, 3, ko1); }
    BAR(); SBAR();
    __builtin_amdgcn_s_setprio(1);
    CLUSTER(6, 7, afB)
    __builtin_amdgcn_s_setprio(0);
    if (st) VM(2);
    BAR();
  }

  // epilogue: D' rows = spatial (lane>>4)*4+j, cols = cout (lane&15)
  const int col = lane & 15;
  const int rg  = lane >> 4;
  int nb[4], hwb[4];
#pragma unroll
  for (int nf = 0; nf < 4; ++nf) {
    int m16 = s0 + wn * 64 + nf * 16;     // 16-aligned; 3136 % 16 == 0
    int n = m16 / HWIMG;
    nb[nf]  = n;
    hwb[nf] = m16 - n * HWIMG + rg * 4;
  }
#pragma unroll
  for (int mi = 0; mi < 8; ++mi) {
    int cc = (mi >> 1) * 64 + wm * 32 + (mi & 1) * 16 + col;
    float bv = bias[cc];
#pragma unroll
    for (int nf = 0; nf < 4; ++nf) {
      float4 v;
      v.x = acc[mi][nf][0] + bv;
      v.y = acc[mi][nf][1] + bv;
      v.z = acc[mi][nf][2] + bv;
      v.w = acc[mi][nf][3] + bv;
      *reinterpret_cast<float4*>(out + ((size_t)nb[nf] * COUT + cc) * HWIMG + hwb[nf]) = v;
    }
  }
#undef STAGE_A
#undef STAGE_B
#undef AF_LOAD
#undef CLUSTER
#undef BAR
#undef SBAR
#undef VM
}

extern "C" void kernel_launch(void* const* d_in, const int* in_sizes, int n_in,
                              void* d_out, int out_size, void* d_ws, size_t ws_size,
                              hipStream_t stream) {
  const float* x = (const float*)d_in[0];
  const float* w = (const float*)d_in[1];
  const float* b = (const float*)d_in[2];
  float* out = (float*)d_out;

  const size_t xp_elems = (size_t)NIMG * HPAD * HPAD * CIN;
  __hip_bfloat16* xp = (__hip_bfloat16*)d_ws;
  __hip_bfloat16* wt = xp + xp_elems;

  prep_all<<<NIMG * HPAD + (COUT * KTOT) / 256, 256, 0, stream>>>(x, w, xp, wt);
  bconv<<<MTOT / BN, 512, 0, stream>>>((const short*)xp, (const short*)wt, b, out);
}

// Round 5
// 89.153 us; speedup vs baseline: 1.1056x; 1.1056x over previous
//
#include <hip/hip_runtime.h>
#include <hip/hip_bf16.h>

typedef __attribute__((ext_vector_type(8))) short bf16x8;
typedef __attribute__((ext_vector_type(4))) float f32x4;

#define CIN   128
#define COUT  256
#define NIMG  32
#define HWDIM 56
#define HPAD  58
#define KTOT  1152            // 9*128
#define HWIMG 3136
#define MTOT  100352
#define BK    64
#define NT    18

__device__ __forceinline__ void gload16(const void* g, void* l) {
  __builtin_amdgcn_global_load_lds((const __attribute__((address_space(1))) void*)g,
                                   (__attribute__((address_space(3))) void*)l,
                                   16, 0, 0);
}

// ---------------- fused pre-pass: halo zero + x->NHWC bf16 + sign(w) ------
__global__ __launch_bounds__(256)
void prep_all(const float* __restrict__ x, const float* __restrict__ w,
              __hip_bfloat16* __restrict__ xp, __hip_bfloat16* __restrict__ wt) {
  __shared__ float tile[CIN * 57];
  const int bid = blockIdx.x;
  const int t = threadIdx.x;
  if (bid < NIMG * HPAD) {
    const int n = bid / HPAD;
    const int h = bid - n * HPAD;
    __hip_bfloat16* dstrow = xp + ((size_t)n * HPAD + h) * HPAD * CIN;
    int4 z; z.x = 0; z.y = 0; z.z = 0; z.w = 0;
    if (h == 0 || h == HPAD - 1) {
      for (int i = t; i < (HPAD * CIN) / 8; i += 256)
        reinterpret_cast<int4*>(dstrow)[i] = z;
      return;
    }
    const float* src = x + (size_t)n * CIN * HWIMG + (size_t)(h - 1) * HWDIM;
    for (int i = t; i < CIN * HWDIM; i += 256) {
      int c = i / HWDIM;
      int wd = i - c * HWDIM;
      tile[c * 57 + wd] = src[(size_t)c * HWIMG + wd];
    }
    if (t < 32) {
      int side = t >> 4;
      reinterpret_cast<int4*>(dstrow + (side ? (HPAD - 1) : 0) * CIN)[t & 15] = z;
    }
    __syncthreads();
    __hip_bfloat16* dst = dstrow + CIN;
    for (int o = t; o < HWDIM * 64; o += 256) {
      int wd = o >> 6;
      int c = (o & 63) * 2;
      __hip_bfloat162 pr;
      pr.x = __float2bfloat16(tile[c * 57 + wd]);
      pr.y = __float2bfloat16(tile[(c + 1) * 57 + wd]);
      *reinterpret_cast<__hip_bfloat162*>(dst + (size_t)wd * CIN + c) = pr;
    }
  } else {
    int o = (bid - NIMG * HPAD) * 256 + t;
    int cout = o / KTOT;
    int r = o - cout * KTOT;
    int tap = r >> 7;
    int cin = r & 127;
    float v = w[((size_t)cout * CIN + cin) * 9 + tap];
    wt[o] = __float2bfloat16(v > 0.f ? 1.f : (v < 0.f ? -1.f : 0.f));
  }
}

// ---------------- main: 128x128 tile, BK=64, 4 blocks/CU ------------------
// R1-proven simple 2-barrier loop; occupancy is the latency-hiding mechanism.
__global__ __launch_bounds__(256, 4)
void bconv(const short* __restrict__ xp, const short* __restrict__ wt,
           const float* __restrict__ bias, float* __restrict__ out) {
  __shared__ short lw[128 * BK];   // 16 KB (A: weights)
  __shared__ short lx[128 * BK];   // 16 KB (B: x)

  const int tid  = threadIdx.x;
  const int lane = tid & 63;
  const int wv   = tid >> 6;      // 0..3
  const int wm   = wv >> 1;       // cout half
  const int wn   = wv & 1;        // spatial half

  // bijective XCD swizzle: pair both cout-halves of a 98-block spatial chunk
  // per XCD -> per-XCD xp slice ~3.2 MB (L2-resident). 1568 % 8 == 0.
  const int myid = blockIdx.y * 784 + blockIdx.x;
  const int sid  = (myid & 7) * 196 + (myid >> 3);
  const int s0   = (sid >> 1) * 128;
  const int f0   = (sid & 1) * 128;

  // staging: 8 threads/row, 32 rows/round, 4 rounds; swizzled global source
  const int srow = tid >> 3;      // 0..31
  const int slot = tid & 7;
  const int swz  = slot ^ (srow & 7);

  int xoff[4];
  int woff[4];
#pragma unroll
  for (int r = 0; r < 4; ++r) {
    int m  = s0 + r * 32 + srow;
    int n  = m / HWIMG;
    int hw = m - n * HWIMG;
    int h  = hw / HWDIM;
    int w  = hw - h * HWDIM;
    xoff[r] = ((n * HPAD + h) * HPAD + w) * CIN + swz * 8;
    woff[r] = (f0 + r * 32 + srow) * KTOT + swz * 8;
  }

  f32x4 acc[4][4] = {};

  short* lwdst = &lw[(wv * 8) * BK];
  short* lxdst = &lx[(wv * 8) * BK];

  for (int ks = 0; ks < NT; ++ks) {
    const int tap = ks >> 1;
    const int kh  = tap / 3;
    const int kw  = tap - kh * 3;
    const int xko = (kh * HPAD + kw) * CIN + (ks & 1) * BK;
    const int wko = ks * BK;

    __syncthreads();
#pragma unroll
    for (int r = 0; r < 4; ++r) {
      gload16(wt + woff[r] + wko, lwdst + r * 32 * BK);
      gload16(xp + xoff[r] + xko, lxdst + r * 32 * BK);
    }
    __syncthreads();

    const int rlo = lane & 15;
#pragma unroll
    for (int ksub = 0; ksub < 2; ++ksub) {
      const int sx = (ksub * 4 + (lane >> 4)) ^ (rlo & 7);
      bf16x8 af[4], bx[4];
#pragma unroll
      for (int f = 0; f < 4; ++f)
        af[f] = *(const bf16x8*)&lw[(wm * 64 + f * 16 + rlo) * BK + sx * 8];
#pragma unroll
      for (int f = 0; f < 4; ++f)
        bx[f] = *(const bf16x8*)&lx[(wn * 64 + f * 16 + rlo) * BK + sx * 8];
      // swapped operands: D rows = spatial (bx), cols = cout (af)
#pragma unroll
      for (int fm = 0; fm < 4; ++fm)
#pragma unroll
        for (int fn = 0; fn < 4; ++fn)
          acc[fm][fn] = __builtin_amdgcn_mfma_f32_16x16x32_bf16(
              bx[fn], af[fm], acc[fm][fn], 0, 0, 0);
    }
  }

  // epilogue: D rows = spatial (rg*4+j consecutive hw), cols = cout (lane&15)
  const int col = lane & 15;
  const int rg  = lane >> 4;
  int nb[4], hwb[4];
#pragma unroll
  for (int fn = 0; fn < 4; ++fn) {
    int m16 = s0 + wn * 64 + fn * 16;    // 16-aligned; 3136 % 16 == 0
    int n = m16 / HWIMG;
    nb[fn]  = n;
    hwb[fn] = m16 - n * HWIMG + rg * 4;
  }
#pragma unroll
  for (int fm = 0; fm < 4; ++fm) {
    int cc = f0 + wm * 64 + fm * 16 + col;
    float bv = bias[cc];
#pragma unroll
    for (int fn = 0; fn < 4; ++fn) {
      float4 v;
      v.x = acc[fm][fn][0] + bv;
      v.y = acc[fm][fn][1] + bv;
      v.z = acc[fm][fn][2] + bv;
      v.w = acc[fm][fn][3] + bv;
      *reinterpret_cast<float4*>(out + ((size_t)nb[fn] * COUT + cc) * HWIMG + hwb[fn]) = v;
    }
  }
}

extern "C" void kernel_launch(void* const* d_in, const int* in_sizes, int n_in,
                              void* d_out, int out_size, void* d_ws, size_t ws_size,
                              hipStream_t stream) {
  const float* x = (const float*)d_in[0];
  const float* w = (const float*)d_in[1];
  const float* b = (const float*)d_in[2];
  float* out = (float*)d_out;

  const size_t xp_elems = (size_t)NIMG * HPAD * HPAD * CIN;
  __hip_bfloat16* xp = (__hip_bfloat16*)d_ws;
  __hip_bfloat16* wt = xp + xp_elems;

  prep_all<<<NIMG * HPAD + (COUT * KTOT) / 256, 256, 0, stream>>>(x, w, xp, wt);

  dim3 grid(MTOT / 128, COUT / 128);
  bconv<<<grid, 256, 0, stream>>>((const short*)xp, (const short*)wt, b, out);
}